// Round 3
// baseline (667.609 us; speedup 1.0000x reference)
//
#include <hip/hip_runtime.h>
#include <hip/hip_bf16.h>
#include <math.h>

#define VOCABN 32000
#define EPSF 0.1f
#define NB 4
#define NT 1024
#define NROWS (NB * (NT - 1))   // 4092 token rows

typedef float f4 __attribute__((ext_vector_type(4)));  // native vector: OK for nontemporal builtin

struct Consts { float scale; float sbase; };

// ---------------------------------------------------------------------------
// Kernel 1: one block. su = sum(histo); scale = EPS/su;
//           sbase = sum_v e*log(e) with e = scale*histo[v].
// ---------------------------------------------------------------------------
__global__ __launch_bounds__(1024) void prep_kernel(const float* __restrict__ histo,
                                                    Consts* __restrict__ c) {
    __shared__ float red[1024];
    int tid = threadIdx.x;

    float s = 0.f;
    for (int v = tid; v < VOCABN; v += 1024) s += histo[v];
    red[tid] = s;
    __syncthreads();
    for (int off = 512; off > 0; off >>= 1) {
        if (tid < off) red[tid] += red[tid + off];
        __syncthreads();
    }
    __shared__ float sc;
    if (tid == 0) sc = EPSF / red[0];
    __syncthreads();
    float scale = sc;

    float sb = 0.f;
    for (int v = tid; v < VOCABN; v += 1024) {
        float e = scale * histo[v];
        sb += e * logf(e);
    }
    __syncthreads();           // ensure red[0] consumed before overwrite
    red[tid] = sb;
    __syncthreads();
    for (int off = 512; off > 0; off >>= 1) {
        if (tid < off) red[tid] += red[tid + off];
        __syncthreads();
    }
    if (tid == 0) { c->scale = scale; c->sbase = red[0]; }
}

// ---------------------------------------------------------------------------
// Kernel 2: one 320-thread block per token row.
//   dot = sum_v histo[v]*__logf(p[v])  (scaled once at the end)
//   kl  = [sbase - e_lab*log(e_lab) + (e_lab+0.9)*log(e_lab+0.9)]
//         - [scale*dot + 0.9*log(p[lab])]
// 8000 float4 per row, 320 threads -> exactly 25 iterations, coalesced.
// ---------------------------------------------------------------------------
__global__ __launch_bounds__(320) void row_kernel(const int* __restrict__ dec_input,
                                                  const float* __restrict__ dec_output,
                                                  const float* __restrict__ histo,
                                                  const Consts* __restrict__ c,
                                                  float* __restrict__ kls) {
    int row = blockIdx.x;                 // 0..4091
    int b   = row / (NT - 1);
    int t   = row - b * (NT - 1);         // 0..1022
    int tid = threadIdx.x;

    int lab = dec_input[b * NT + t + 1];
    if (lab == 0) {                       // PAD -> masked out
        if (tid == 0) kls[row] = 0.f;
        return;
    }

    const float* prow = dec_output + (size_t)(b * NT + t) * VOCABN;
    const f4*    p4   = (const f4*)prow;
    const f4*    h4   = (const f4*)histo;

    // 4 accumulators to shorten the dependent-add chain.
    float a0 = 0.f, a1 = 0.f, a2 = 0.f, a3 = 0.f;
    #pragma unroll 5
    for (int i = 0; i < 25; ++i) {
        int idx = tid + i * 320;
        f4 pv = __builtin_nontemporal_load(&p4[idx]);  // streamed once, bypass cache retention
        f4 hv = h4[idx];                               // cached / reused
        a0 += hv.x * __logf(pv.x);
        a1 += hv.y * __logf(pv.y);
        a2 += hv.z * __logf(pv.z);
        a3 += hv.w * __logf(pv.w);
    }
    float local = (a0 + a1) + (a2 + a3);

    // wave (64-lane) shuffle reduce, then LDS across the 5 waves
    for (int off = 32; off > 0; off >>= 1) local += __shfl_down(local, off, 64);
    __shared__ float wsum[5];
    if ((tid & 63) == 0) wsum[tid >> 6] = local;
    __syncthreads();

    if (tid == 0) {
        float scale = c->scale;
        float dot   = (wsum[0] + wsum[1] + wsum[2] + wsum[3] + wsum[4]) * scale;
        float plab  = prow[lab];
        float elab  = scale * histo[lab];
        float qlab  = elab + (1.f - EPSF);
        float qlogq = c->sbase - elab * logf(elab) + qlab * logf(qlab);
        float qlogp = dot + (1.f - EPSF) * logf(plab);
        kls[row] = qlogq - qlogp;
    }
}

// ---------------------------------------------------------------------------
// Kernel 3: deterministic double-precision mean over the 4092 row KLs.
// ---------------------------------------------------------------------------
__global__ __launch_bounds__(1024) void fin_kernel(const float* __restrict__ kls,
                                                   float* __restrict__ out) {
    __shared__ double red[1024];
    int tid = threadIdx.x;
    double s = 0.0;
    for (int i = tid; i < NROWS; i += 1024) s += (double)kls[i];
    red[tid] = s;
    __syncthreads();
    for (int off = 512; off > 0; off >>= 1) {
        if (tid < off) red[tid] += red[tid + off];
        __syncthreads();
    }
    if (tid == 0) out[0] = (float)(red[0] / (double)NROWS);
}

extern "C" void kernel_launch(void* const* d_in, const int* in_sizes, int n_in,
                              void* d_out, int out_size, void* d_ws, size_t ws_size,
                              hipStream_t stream) {
    const int*   dec_input  = (const int*)d_in[0];
    const float* dec_output = (const float*)d_in[1];
    const float* histo      = (const float*)d_in[2];

    float*  kls = (float*)d_ws;                       // NROWS floats (16368 B)
    Consts* c   = (Consts*)((char*)d_ws + 16384);     // aligned past kls

    prep_kernel<<<1, 1024, 0, stream>>>(histo, c);
    row_kernel<<<NROWS, 320, 0, stream>>>(dec_input, dec_output, histo, c, kls);
    fin_kernel<<<1, 1024, 0, stream>>>(kls, (float*)d_out);
}